// Round 12
// baseline (170.112 us; speedup 1.0000x reference)
//
#include <hip/hip_runtime.h>
#include <math.h>

#define HH 96
#define WW 96
#define CC 64
#define NH 4
#define HD 16
#define KS 13
#define KK (KS*KS)
#define NTOK (HH*WW)

// ---------------- DPP cross-lane add (pure VALU, no LDS pipe) ---------------
// ctrl 0xB1 = quad_perm(1,0,3,2)  -> xor1 within quad
// ctrl 0x4E = quad_perm(2,3,0,1)  -> xor2 within quad
// ctrl 0x124 = row_ror:4, 0x128 = row_ror:8 (full-group sums: direction moot)
// ctrl 0x141 = row_half_mirror, 0x140 = row_mirror (valid when sub-groups
// already uniform)
template<int CTRL>
__device__ __forceinline__ float dpp_add(float p) {
    int t = __builtin_amdgcn_update_dpp(0, __float_as_int(p), CTRL, 0xF, 0xF, true);
    return p + __int_as_float(t);
}

__device__ __forceinline__ float dpp_reduce8(float p) {
    p = dpp_add<0xB1>(p);
    p = dpp_add<0x4E>(p);
    p = dpp_add<0x141>(p);
    return p;
}

// In-place LayerNorm of a 32-token tile stored TRANSPOSED in LDS: buf[ch][tok],
// ch = 0..63, tok = 0..31. 256 threads: 8 lanes per row, 8 channels per lane.
template<int PITCH>
__device__ __forceinline__ void ln_rows32(float (*buf)[PITCH],
                                          const float* __restrict__ g,
                                          const float* __restrict__ b,
                                          int tid) {
    int r  = tid >> 3;
    int c0 = (tid & 7) * 8;
    float v[8];
    float s = 0.0f;
    #pragma unroll
    for (int j = 0; j < 8; j++) { v[j] = buf[c0 + j][r]; s += v[j]; }
    s = dpp_reduce8(s);
    float mu = s * (1.0f / 64.0f);
    float s2 = 0.0f;
    #pragma unroll
    for (int j = 0; j < 8; j++) { float d = v[j] - mu; s2 += d * d; }
    s2 = dpp_reduce8(s2);
    float inv = rsqrtf(s2 * (1.0f / 64.0f) + 1e-5f);
    #pragma unroll
    for (int j = 0; j < 8; j++)
        buf[c0 + j][r] = (v[j] - mu) * inv * g[c0 + j] + b[c0 + j];
}

// ---------------- Fused LN1 + qkv GEMM (unchanged) --------------------------
__global__ __launch_bounds__(256) void ln_gemm_kernel(const float* __restrict__ x,
                                                      const float* __restrict__ g,
                                                      const float* __restrict__ b,
                                                      const float* __restrict__ W,
                                                      const float* __restrict__ bias,
                                                      float* __restrict__ out) {
    __shared__ float Ast[64][34];
    const int t0 = blockIdx.x * 32;
    const int tid = threadIdx.x;

    for (int i = tid; i < 32 * 64; i += 256) {
        int r = i >> 6, cc = i & 63;
        Ast[cc][r] = x[t0 * 64 + i];
    }
    __syncthreads();
    ln_rows32<34>(Ast, g, b, tid);
    __syncthreads();

    const int tc = tid & 15;
    const int tr = tid >> 4;
    const int r0 = tr * 2;
    const int c  = blockIdx.y * 64 + tc * 4;

    float4 b4 = *(const float4*)&bias[c];
    float4 acc0 = b4, acc1 = b4;
    #pragma unroll 8
    for (int k = 0; k < 64; k++) {
        float2 a = *(const float2*)&Ast[k][r0];
        float4 w = *(const float4*)&W[k * 192 + c];
        acc0.x += a.x * w.x; acc0.y += a.x * w.y; acc0.z += a.x * w.z; acc0.w += a.x * w.w;
        acc1.x += a.y * w.x; acc1.y += a.y * w.y; acc1.z += a.y * w.z; acc1.w += a.y * w.w;
    }
    if (blockIdx.y == 0) {  // q section scaled by hd^-0.5 = 0.25
        acc0.x *= 0.25f; acc0.y *= 0.25f; acc0.z *= 0.25f; acc0.w *= 0.25f;
        acc1.x *= 0.25f; acc1.y *= 0.25f; acc1.z *= 0.25f; acc1.w *= 0.25f;
    }
    *(float4*)&out[(t0 + r0) * 192 + c] = acc0;
    *(float4*)&out[(t0 + r0 + 1) * 192 + c] = acc1;
}

// ---------------- Neighborhood attention (unchanged from R8) ----------------
__global__ __launch_bounds__(256) void na_attn_kernel(const float* __restrict__ qkv,
                                                      const float* __restrict__ rpb,
                                                      float* __restrict__ out) {
    int wave = threadIdx.x >> 6;
    int lane = threadIdx.x & 63;
    int bid  = blockIdx.x;
    int swz  = (bid & 7) * 288 + (bid >> 3);   // bijective: 2304 % 8 == 0
    int y    = swz / 24;                       // spatial row
    int rem  = swz - y * 24;
    int gw   = rem >> 3;                       // dilation group (x % 3)
    int iw   = (rem & 7) * 4 + wave;           // group-col of this wave's token
    int token = y * WW + gw + 3 * iw;

    int head = lane >> 4;
    int slot = (lane >> 2) & 3;
    int l    = lane & 3;
    int co   = head * HD + l * 4;

    int gh = y % 3, ih = y / 3;
    int sh = ih - 6; sh = sh < 0 ? 0 : (sh > 19 ? 19 : sh);
    int sw = iw - 6; sw = sw < 0 ? 0 : (sw > 19 ? 19 : sw);

    float4 q4 = *(const float4*)&qkv[token * 192 + co];
    const float* bias_h = rpb + head * 625 + (sw - iw + 12);

    const int xpart = (gw + 3 * sw) * 192 + 64 + co + slot * 576;

    float4 acc = make_float4(0.f, 0.f, 0.f, 0.f);
    float s = 0.0f;

    for (int kh = 0; kh < KS; kh++) {
        int ny = gh + 3 * (sh + kh);
        const float* kp = qkv + ny * (WW * 192) + xpart;
        const float* bp = bias_h + (sh + kh - ih + 12) * 25;
        #pragma unroll
        for (int i = 0; i < 3; i++) {          // kw = 4*i + slot : 0..11
            float4 k4 = *(const float4*)(kp + i * 2304);
            float4 v4 = *(const float4*)(kp + i * 2304 + 64);
            float p = q4.x * k4.x + q4.y * k4.y + q4.z * k4.z + q4.w * k4.w;
            p = dpp_add<0xB1>(p);
            p = dpp_add<0x4E>(p);              // p = 16-dim dot (quad sum)
            float e = __expf(p + bp[4 * i + slot]);
            s += e;
            acc.x += e * v4.x; acc.y += e * v4.y; acc.z += e * v4.z; acc.w += e * v4.w;
        }
        if (slot == 0) {                        // tail kw = 12 (quad-uniform branch)
            float4 k4 = *(const float4*)(kp + 3 * 2304);
            float4 v4 = *(const float4*)(kp + 3 * 2304 + 64);
            float p = q4.x * k4.x + q4.y * k4.y + q4.z * k4.z + q4.w * k4.w;
            p = dpp_add<0xB1>(p);
            p = dpp_add<0x4E>(p);
            float e = __expf(p + bp[12]);
            s += e;
            acc.x += e * v4.x; acc.y += e * v4.y; acc.z += e * v4.z; acc.w += e * v4.w;
        }
    }

    s = dpp_add<0x128>(s);  s = dpp_add<0x124>(s);
    acc.x = dpp_add<0x128>(acc.x); acc.x = dpp_add<0x124>(acc.x);
    acc.y = dpp_add<0x128>(acc.y); acc.y = dpp_add<0x124>(acc.y);
    acc.z = dpp_add<0x128>(acc.z); acc.z = dpp_add<0x124>(acc.z);
    acc.w = dpp_add<0x128>(acc.w); acc.w = dpp_add<0x124>(acc.w);

    if (slot == 0) {
        float inv = 1.0f / s;
        *(float4*)&out[token * CC + co] =
            make_float4(acc.x * inv, acc.y * inv, acc.z * inv, acc.w * inv);
    }
}

// ---------------- Fused proj+resid -> LN2 -> fc1+gelu -> fc2+resid ----------
// v4. Evidence-driven model: time ~ max(issued-L1 / ~15 TB/s, latency floor
// when waves/SIMD < ~1). R8 (2 rows/thr, 4 waves/blk): traffic-bound 42 us.
// v3 (4 rows/thr, 2 waves/blk): traffic halved but 0.5 wave/SIMD -> latency
// floor 43.7 us (7.6 TB/s effective, VALUBusy 12%). v4 keeps v3's 4
// rows/thread (low traffic ~331 MB) but with 256 threads = 4 waves/block:
// each thread 4 rows x 2 cols, float2 weight loads (same bytes, 2x lanes).
// Thread map: tc = tid&31 (col pair 2tc), tr = tid>>5 (rows 4tr..4tr+3).
// Pitch 36: &buf[k][4tr] is 16B-aligned -> ds_read_b128 of 4 rows.
__global__ __launch_bounds__(256) void mlp_fused_kernel(const float* __restrict__ attn_out,
                                                        const float* __restrict__ x,
                                                        const float* __restrict__ proj_w,
                                                        const float* __restrict__ proj_b,
                                                        const float* __restrict__ n2g,
                                                        const float* __restrict__ n2b,
                                                        const float* __restrict__ fc1_w,
                                                        const float* __restrict__ fc1_b,
                                                        const float* __restrict__ fc2_w,
                                                        const float* __restrict__ fc2_b,
                                                        float* __restrict__ out) {
    __shared__ float Ast[64][36];    // attn_out^T tile      (9.2 KB)
    __shared__ float X2T[64][36];    // x2^T -> h2^T          (9.2 KB)
    __shared__ float Hid[256][36];   // hidden^T              (36.9 KB)

    const int t0 = blockIdx.x * 32;
    const int tid = threadIdx.x;
    const int tc = tid & 31;         // col pair: cols 2tc, 2tc+1
    const int tr = tid >> 5;         // row group 0..7: rows 4tr..4tr+3
    const int r0 = tr * 4;
    const int c2 = tc * 2;

    // stage attn_out tile transposed: 512 float4s, 2 per thread, coalesced
    #pragma unroll
    for (int j = 0; j < 2; j++) {
        int idx = tid + 256 * j;                 // float4 index 0..511
        float4 v = ((const float4*)attn_out)[t0 * 16 + idx];
        int row = idx >> 4, cc = (idx & 15) * 4;
        Ast[cc][row] = v.x; Ast[cc + 1][row] = v.y;
        Ast[cc + 2][row] = v.z; Ast[cc + 3][row] = v.w;
    }
    __syncthreads();

    // ---- proj + residual(x): x2 rows r0..r0+3 (cols c2,c2+1) in a[4] ----
    float2 pb = *(const float2*)&proj_b[c2];
    float2 a[4] = {pb, pb, pb, pb};
    #pragma unroll 8
    for (int k = 0; k < 64; k++) {
        float4 aa = *(const float4*)&Ast[k][r0];     // rows r0..r0+3
        float  ar[4] = {aa.x, aa.y, aa.z, aa.w};
        float2 w = *(const float2*)&proj_w[k * 64 + c2];
        #pragma unroll
        for (int i = 0; i < 4; i++) {
            a[i].x += ar[i] * w.x; a[i].y += ar[i] * w.y;
        }
    }
    {
        float4 cx, cy;   // x2 column vectors (rows r0..r0+3) for the 2 cols
        #pragma unroll
        for (int i = 0; i < 4; i++) {
            float2 xr = *(const float2*)&x[(t0 + r0 + i) * 64 + c2];
            a[i].x += xr.x; a[i].y += xr.y;
        }
        cx = make_float4(a[0].x, a[1].x, a[2].x, a[3].x);
        cy = make_float4(a[0].y, a[1].y, a[2].y, a[3].y);
        *(float4*)&X2T[c2][r0]     = cx;   // col c2, rows r0..r0+3
        *(float4*)&X2T[c2 + 1][r0] = cy;
    }
    __syncthreads();

    // ---- LN2 in place on X2T (256 thr: 8 lanes/row, 8 ch/lane) ----
    ln_rows32<36>(X2T, n2g, n2b, tid);
    __syncthreads();

    // ---- fc1 + gelu -> Hid. Thread: 4 rows x 8 cols (4 gg x float2) ----
    float2 h[4][4];                  // h[row][gg]
    #pragma unroll
    for (int gg = 0; gg < 4; gg++) {
        float2 bb = *(const float2*)&fc1_b[c2 + gg * 64];
        #pragma unroll
        for (int i = 0; i < 4; i++) h[i][gg] = bb;
    }
    #pragma unroll 4
    for (int k = 0; k < 64; k++) {
        float4 aa = *(const float4*)&X2T[k][r0];
        float  ar[4] = {aa.x, aa.y, aa.z, aa.w};
        #pragma unroll
        for (int gg = 0; gg < 4; gg++) {
            float2 w = *(const float2*)&fc1_w[k * 256 + c2 + gg * 64];
            #pragma unroll
            for (int i = 0; i < 4; i++) {
                h[i][gg].x += ar[i] * w.x; h[i][gg].y += ar[i] * w.y;
            }
        }
    }
    #define GELU1(v) v = 0.5f * v * (1.0f + erff(v * 0.70710678118f))
    #pragma unroll
    for (int i = 0; i < 4; i++)
        #pragma unroll
        for (int gg = 0; gg < 4; gg++) { GELU1(h[i][gg].x); GELU1(h[i][gg].y); }
    #undef GELU1
    #pragma unroll
    for (int gg = 0; gg < 4; gg++) {
        *(float4*)&Hid[c2 + gg * 64][r0] =
            make_float4(h[0][gg].x, h[1][gg].x, h[2][gg].x, h[3][gg].x);
        *(float4*)&Hid[c2 + 1 + gg * 64][r0] =
            make_float4(h[0][gg].y, h[1][gg].y, h[2][gg].y, h[3][gg].y);
    }
    __syncthreads();

    // ---- fc2 + residual(x2 from registers a[4]) ----
    float2 ob = *(const float2*)&fc2_b[c2];
    float2 o[4] = {ob, ob, ob, ob};
    #pragma unroll 8
    for (int k = 0; k < 256; k++) {
        float4 aa = *(const float4*)&Hid[k][r0];
        float  ar[4] = {aa.x, aa.y, aa.z, aa.w};
        float2 w = *(const float2*)&fc2_w[k * 64 + c2];
        #pragma unroll
        for (int i = 0; i < 4; i++) {
            o[i].x += ar[i] * w.x; o[i].y += ar[i] * w.y;
        }
    }
    #pragma unroll
    for (int i = 0; i < 4; i++) {
        o[i].x += a[i].x; o[i].y += a[i].y;
        *(float2*)&out[(t0 + r0 + i) * 64 + c2] = o[i];
    }
}

extern "C" void kernel_launch(void* const* d_in, const int* in_sizes, int n_in,
                              void* d_out, int out_size, void* d_ws, size_t ws_size,
                              hipStream_t stream) {
    const float* x       = (const float*)d_in[0];
    const float* norm1_g = (const float*)d_in[1];
    const float* norm1_b = (const float*)d_in[2];
    const float* qkv_w   = (const float*)d_in[3];
    const float* qkv_b   = (const float*)d_in[4];
    const float* rpb     = (const float*)d_in[5];
    const float* proj_w  = (const float*)d_in[6];
    const float* proj_b  = (const float*)d_in[7];
    const float* norm2_g = (const float*)d_in[8];
    const float* norm2_b = (const float*)d_in[9];
    const float* fc1_w   = (const float*)d_in[10];
    const float* fc1_b   = (const float*)d_in[11];
    const float* fc2_w   = (const float*)d_in[12];
    const float* fc2_b   = (const float*)d_in[13];
    float* out = (float*)d_out;

    float* ws = (float*)d_ws;
    float* qkv      = ws;                      // 9216*192
    float* attn_out = qkv + NTOK * 192;        // 9216*64

    dim3 blk(256);
    // 1. qkv = LN1(x) @ qkv_w + qkv_b   (q pre-scaled)
    ln_gemm_kernel<<<dim3(NTOK / 32, 3), blk, 0, stream>>>(x, norm1_g, norm1_b, qkv_w, qkv_b, qkv);
    // 2. neighborhood attention (1 token/wave; block = 4 window-sharing tokens)
    na_attn_kernel<<<NTOK / 4, blk, 0, stream>>>(qkv, rpb, attn_out);
    // 3. out = fused MLP: 32 tok/block, 256 thr, 4 rows x 2 cols per thread
    mlp_fused_kernel<<<NTOK / 32, blk, 0, stream>>>(attn_out, x, proj_w, proj_b,
                                                    norm2_g, norm2_b, fc1_w, fc1_b,
                                                    fc2_w, fc2_b, out);
}